// Round 5
// baseline (112.922 us; speedup 1.0000x reference)
//
#include <hip/hip_runtime.h>
#include <math.h>

#define BATCH 4
#define HLR 256
#define WLR 256
#define HHR 512
#define WHR 512

typedef short s8v __attribute__((ext_vector_type(8)));
typedef float f4v __attribute__((ext_vector_type(4)));

__device__ __forceinline__ ushort f2bf(float f) {
    uint u = __builtin_bit_cast(uint, f);
    uint r = (u + 0x7FFFu + ((u >> 16) & 1u)) >> 16;
    return (ushort)r;
}
__device__ __forceinline__ float bf2f(ushort u) {
    return __builtin_bit_cast(float, ((uint)u) << 16);
}

// ---------------- Kernel 1: FUSED bicubic down x2 + gain + bilateral + gamma -------
// Block = 16x16 outputs of one (b,c) plane. Phase 1: compute 20x20 downsampled halo
// into LDS (1.56x recompute, trivially cheap). Phase 2: 5x5 bilateral from LDS.
// Reflect indices at image borders stay within the staged tile (reflect(-2)=+2).
__global__ void __launch_bounds__(256) k_downbil(
    const float* __restrict__ x, const float* __restrict__ gains,
    const float* __restrict__ sigp, const float* __restrict__ gamp,
    float* __restrict__ xlr) {
    __shared__ float tile[20][20];
    const int tid = threadIdx.x;
    const int tx = tid & 15, ty = tid >> 4;
    const int w0 = blockIdx.x * 16, h0 = blockIdx.y * 16;
    const int bc = blockIdx.z;
    const int c = bc % 3;
    const float* src = x + (size_t)bc * (HHR * WHR);
    const float gain = gains[c];

    const float cw0 = -0.09375f, cw1 = 0.59375f, cw2 = 0.59375f, cw3 = -0.09375f;
    // phase 1: downsample 20x20 halo (LR coords h0-2..h0+17 x w0-2..w0+17)
    for (int i = tid; i < 400; i += 256) {
        int r = i / 20, cc = i - r * 20;
        int hh = h0 + r - 2, ww = w0 + cc - 2;
        float acc = 0.f;
#pragma unroll
        for (int kh = 0; kh < 4; ++kh) {
            int sh = 2 * hh + kh - 1;
            sh = sh < 0 ? 0 : (sh > HHR - 1 ? HHR - 1 : sh);
            const float* row = src + (size_t)sh * WHR;
            float rr = 0.f;
#pragma unroll
            for (int kw = 0; kw < 4; ++kw) {
                int sw = 2 * ww + kw - 1;
                sw = sw < 0 ? 0 : (sw > WHR - 1 ? WHR - 1 : sw);
                float wk = (kw == 0) ? cw0 : (kw == 1) ? cw1 : (kw == 2) ? cw2 : cw3;
                rr = fmaf(wk, row[sw], rr);
            }
            float wk = (kh == 0) ? cw0 : (kh == 1) ? cw1 : (kh == 2) ? cw2 : cw3;
            acc = fmaf(wk, rr, acc);
        }
        tile[r][cc] = acc * gain;
    }
    __syncthreads();

    // phase 2: bilateral at (h0+ty, w0+tx)
    const int h = h0 + ty, w = w0 + tx;
    float sigma = sigp[0];
    float inv2s2 = 1.0f / (2.0f * sigma * sigma);
    float invg = 1.0f / gamp[0];
    const float sp0 = 0.13533528f;  // exp(-2)
    const float sp1 = 0.60653066f;  // exp(-0.5)

    float center = tile[ty + 2][tx + 2];
    float wsum = 0.f, psum = 0.f;
#pragma unroll
    for (int i = 0; i < 5; ++i) {
        int sh = h + i - 2;
        sh = sh < 0 ? -sh : (sh > HLR - 1 ? 2 * (HLR - 1) - sh : sh);  // reflect
        int lr = sh - h0 + 2;  // in [0,19] by construction
        float spi = (i == 0 || i == 4) ? sp0 : (i == 2 ? 1.0f : sp1);
#pragma unroll
        for (int j = 0; j < 5; ++j) {
            int sw = w + j - 2;
            sw = sw < 0 ? -sw : (sw > WLR - 1 ? 2 * (WLR - 1) - sw : sw);
            int lc = sw - w0 + 2;
            float spj = (j == 0 || j == 4) ? sp0 : (j == 2 ? 1.0f : sp1);
            float p = tile[lr][lc];
            float d = p - center;
            float cwt = __expf(-d * d * inv2s2) * spi * spj;
            wsum += cwt;
            psum = fmaf(cwt, p, psum);
        }
    }
    float v = psum / (wsum + 1e-8f);
    v = fminf(fmaxf(v, 1e-8f), 1.0f);
    xlr[(size_t)bc * (HLR * WLR) + h * WLR + w] = __powf(v, invg);
}

// --------- Effective upsample weight: Av(d, e_idx, t_idx), taps t-1 in {-1..2} -----
__device__ __forceinline__ float Avf(int d, int e, int t) {
    int mm = d + e - 1;
    int par = mm & 1;
    int jr = (mm - par) >> 1;
    int j2 = jr + (par ? 1 : -1);
    float a = 0.f;
    if (t == jr + 1) a += 0.75f;
    if (t == j2 + 1) a += 0.25f;
    return a;
}

// ---------------- Merged weight prep: all three B-fragment tensors -----------------
// blocks [0,144): w2 -> Bp2[18][4][64][8]
// blocks [144,208): w3 -> Bp3[32][64][8] (effective 4x4-tap upsample*conv3)
// blocks [208,232): w1 -> Bp1[3][4][64][8], K=96 zero-padded
__global__ void k_prepall(const float* __restrict__ w1, const float* __restrict__ w2,
                          const float* __restrict__ w3, ushort* __restrict__ Bp1,
                          ushort* __restrict__ Bp2, ushort* __restrict__ Bp3) {
    int bx = blockIdx.x;
    if (bx < 144) {
        int tid = bx * 256 + threadIdx.x;
        int j = tid & 7;
        int l = (tid >> 3) & 63;
        int g = (tid >> 9) & 3;
        int s = tid >> 11;
        int k = 32 * s + (l >> 4) * 8 + j;
        int t = k >> 6;
        int ic = k & 63;
        int oc = g * 16 + (l & 15);
        Bp2[tid] = f2bf(w2[(size_t)(oc * 64 + ic) * 9 + t]);
    } else if (bx < 208) {
        int tid = (bx - 144) * 256 + threadIdx.x;
        int j = tid & 7;
        int l = (tid >> 3) & 63;
        int s = tid >> 9;
        int col = l & 15;
        float v = 0.f;
        if (col < 12) {
            int p = col / 3, o = col % 3;
            int dy = p >> 1, dx = p & 1;
            int k = s * 32 + (l >> 4) * 8 + j;
            int tap = k >> 6, ic = k & 63;
            int ty = tap >> 2, tx = tap & 3;
#pragma unroll
            for (int oh = 0; oh < 3; ++oh)
#pragma unroll
                for (int ow = 0; ow < 3; ++ow)
                    v += w3[(size_t)(o * 64 + ic) * 9 + oh * 3 + ow] *
                         Avf(dy, oh, ty) * Avf(dx, ow, tx);
        }
        Bp3[tid] = f2bf(v);
    } else {
        int tid = (bx - 208) * 256 + threadIdx.x;
        int j = tid & 7;
        int l = (tid >> 3) & 63;
        int g = (tid >> 9) & 3;
        int s = tid >> 11;
        int k = s * 32 + (l >> 4) * 8 + j;
        int oc = g * 16 + (l & 15);
        float v = 0.f;
        if (k < 75) {
            int tap = k / 3, ic = k % 3;
            v = w1[(size_t)oc * 75 + ic * 25 + tap];
        }
        Bp1[tid] = f2bf(v);
    }
}

// ---------------- Kernel 3: conv1 3->64, 5x5, pad 2, relu — MFMA implicit GEMM ----
__global__ void __launch_bounds__(256) k_conv1_mfma(
    const float* __restrict__ xlr, const ushort* __restrict__ Bp,
    const float* __restrict__ b1, ushort* __restrict__ y1) {
    __shared__ float rawt[3][8][20];                 // zero-padded halo
    __shared__ __align__(16) ushort Alds[64 * 104];  // 13312 B
    const int tid = threadIdx.x;
    const int w0 = blockIdx.x * 16;
    const int h0 = blockIdx.y * 4;
    const int b = blockIdx.z;

    for (int i = tid; i < 480; i += 256) {
        int ch = i / 160;
        int rem = i - ch * 160;
        int r = rem / 20, c = rem - r * 20;
        int gh = h0 + r - 2, gw = w0 + c - 2;
        float v = 0.f;
        if (gh >= 0 && gh < HLR && gw >= 0 && gw < WLR)
            v = xlr[(size_t)(b * 3 + ch) * (HLR * WLR) + gh * WLR + gw];
        rawt[ch][r][c] = v;
    }
    __syncthreads();

    {
        const int pos = tid >> 2;
        const int kq = tid & 3;
        const int f = pos >> 4;
        const int wl = pos & 15;
#pragma unroll
        for (int m = 0; m < 3; ++m) {
            uint pk[4];
#pragma unroll
            for (int e2 = 0; e2 < 4; ++e2) {
                ushort lo, hi;
#pragma unroll
                for (int h2 = 0; h2 < 2; ++h2) {
                    int i = m * 8 + e2 * 2 + h2;
                    int t0 = i / 3;
                    int ic = i - t0 * 3;
                    int tap = kq * 8 + t0;
                    float val = 0.f;
                    if (tap < 25) {
                        int kh = tap / 5, kw = tap - (tap / 5) * 5;
                        val = rawt[ic][f + kh][wl + kw];
                    }
                    if (h2 == 0) lo = f2bf(val); else hi = f2bf(val);
                }
                pk[e2] = (uint)lo | ((uint)hi << 16);
            }
            *(int4*)(Alds + pos * 104 + kq * 24 + m * 8) =
                make_int4(pk[0], pk[1], pk[2], pk[3]);
        }
    }
    __syncthreads();

    const int lane = tid & 63;
    const int wv = tid >> 6;
    const int l15 = lane & 15;
    const int lgrp = lane >> 4;

    f4v acc[4];
#pragma unroll
    for (int f = 0; f < 4; ++f) acc[f] = (f4v){0.f, 0.f, 0.f, 0.f};

#pragma unroll
    for (int s = 0; s < 3; ++s) {
        s8v bfrag = *(const s8v*)(Bp + ((size_t)(s * 4 + wv) * 64 + lane) * 8);
#pragma unroll
        for (int f = 0; f < 4; ++f) {
            const ushort* ap = Alds + (f * 16 + l15) * 104 + s * 32 + lgrp * 8;
            s8v afrag = *(const s8v*)ap;
            acc[f] = __builtin_amdgcn_mfma_f32_16x16x32_bf16(afrag, bfrag, acc[f], 0, 0, 0);
        }
    }

    int oc = wv * 16 + l15;
    float bias = b1[oc];
    const size_t base = (size_t)b * HLR * WLR * 64;
#pragma unroll
    for (int f = 0; f < 4; ++f) {
        int h = h0 + f;
#pragma unroll
        for (int r = 0; r < 4; ++r) {
            int w = w0 + lgrp * 4 + r;
            float v = fmaxf(acc[f][r] + bias, 0.f);
            y1[base + (size_t)(h * WLR + w) * 64 + oc] = f2bf(v);
        }
    }
}

// ---------------- Kernel 4: conv2 64->64, 3x3, pad1, relu — 16x16 retile -----------
// Block covers 16x16 spatial; wave wv -> rows wv*4..+3, computes ALL 4 oc-groups.
__global__ void __launch_bounds__(256) k_conv2_mfma(
    const ushort* __restrict__ y1, const ushort* __restrict__ Bprep,
    const float* __restrict__ b2, ushort* __restrict__ y2) {
    __shared__ ushort lds[18 * 18 * 64];  // 41472 B
    const int tid = threadIdx.x;
    const int w0 = blockIdx.x * 16;
    const int h0 = blockIdx.y * 16;
    const int b = blockIdx.z;
    const size_t base = (size_t)b * HLR * WLR * 64;

    for (int i = tid; i < 2592; i += 256) {
        int c = i & 7;
        int pos = i >> 3;
        int r = pos / 18;
        int cc = pos - r * 18;
        int gh = h0 + r - 1, gw = w0 + cc - 1;
        int4 v = make_int4(0, 0, 0, 0);
        if (gh >= 0 && gh < HLR && gw >= 0 && gw < WLR)
            v = *(const int4*)(y1 + base + (size_t)(gh * WLR + gw) * 64 + c * 8);
        int byte = pos * 128 + ((c * 16) ^ ((pos & 7) << 4));
        *(int4*)((char*)lds + byte) = v;
    }
    __syncthreads();

    const int lane = tid & 63;
    const int wv = tid >> 6;
    const int l15 = lane & 15;
    const int lgrp = lane >> 4;
    const int rowbase = wv * 4;

    f4v acc[4][4];  // [f][oc-group]
#pragma unroll
    for (int f = 0; f < 4; ++f)
#pragma unroll
        for (int g = 0; g < 4; ++g) acc[f][g] = (f4v){0.f, 0.f, 0.f, 0.f};

#pragma unroll
    for (int s = 0; s < 18; ++s) {
        const int t = s >> 1;
        const int dh = t / 3 - 1;
        const int dw = t % 3 - 1;
        const int icb = (s & 1) * 64 + lgrp * 16;
        s8v bfr[4];
#pragma unroll
        for (int g = 0; g < 4; ++g)
            bfr[g] = *(const s8v*)(Bprep + ((size_t)(s * 4 + g) * 64 + lane) * 8);
#pragma unroll
        for (int f = 0; f < 4; ++f) {
            int sp = (rowbase + f + dh + 1) * 18 + (l15 + dw + 1);
            int byte = sp * 128 + (icb ^ ((sp & 7) << 4));
            s8v afrag = *(const s8v*)((const char*)lds + byte);
#pragma unroll
            for (int g = 0; g < 4; ++g)
                acc[f][g] = __builtin_amdgcn_mfma_f32_16x16x32_bf16(afrag, bfr[g], acc[f][g], 0, 0, 0);
        }
    }

#pragma unroll
    for (int f = 0; f < 4; ++f) {
        int h = h0 + rowbase + f;
#pragma unroll
        for (int g = 0; g < 4; ++g) {
            int oc = g * 16 + l15;
            float bias = b2[oc];
#pragma unroll
            for (int r = 0; r < 4; ++r) {
                int w = w0 + lgrp * 4 + r;
                float v = fmaxf(acc[f][g][r] + bias, 0.f);
                y2[base + (size_t)(h * WLR + w) * 64 + oc] = f2bf(v);
            }
        }
    }
}

// ---------------- Kernel 5: fused upsample+conv3 as MFMA 4x4-tap 64->12 conv -------
__global__ void __launch_bounds__(256) k_upc3_mfma(
    const ushort* __restrict__ y2, const ushort* __restrict__ Bp,
    const float* __restrict__ b3, float* __restrict__ xsr) {
    __shared__ ushort lds[19 * 19 * 64];  // 46208 B
    const int tid = threadIdx.x;
    const int w0 = blockIdx.x * 16;
    const int h0 = blockIdx.y * 16;
    const int b = blockIdx.z;
    const size_t base = (size_t)b * HLR * WLR * 64;

    for (int i = tid; i < 2888; i += 256) {
        int c = i & 7;
        int pos = i >> 3;
        int r = pos / 19, cc = pos - r * 19;
        int gh = h0 + r - 1, gw = w0 + cc - 1;
        gh = gh < 0 ? 0 : (gh > HLR - 1 ? HLR - 1 : gh);
        gw = gw < 0 ? 0 : (gw > WLR - 1 ? WLR - 1 : gw);
        int4 v = *(const int4*)(y2 + base + (size_t)(gh * WLR + gw) * 64 + c * 8);
        int byte = pos * 128 + ((c * 16) ^ ((pos & 7) << 4));
        *(int4*)((char*)lds + byte) = v;
    }
    __syncthreads();

    const int lane = tid & 63;
    const int wv = tid >> 6;
    const int l15 = lane & 15;
    const int lgrp = lane >> 4;
    const int rowbase = wv * 4;

    f4v acc[4];
#pragma unroll
    for (int f = 0; f < 4; ++f) acc[f] = (f4v){0.f, 0.f, 0.f, 0.f};

    const ushort* bp = Bp + (size_t)lane * 8;
#pragma unroll
    for (int s = 0; s < 32; ++s) {
        s8v bfrag = *(const s8v*)(bp + (size_t)s * 512);
        const int tap = s >> 1;
        const int ty = tap >> 2, tx = tap & 3;
        const int icb = (s & 1) * 64 + lgrp * 16;
#pragma unroll
        for (int f = 0; f < 4; ++f) {
            int pos = (rowbase + f + ty) * 19 + (l15 + tx);
            int byte = pos * 128 + (icb ^ ((pos & 7) << 4));
            s8v afrag = *(const s8v*)((const char*)lds + byte);
            acc[f] = __builtin_amdgcn_mfma_f32_16x16x32_bf16(afrag, bfrag, acc[f], 0, 0, 0);
        }
    }

    if (l15 < 12) {
        int p = l15 / 3, o = l15 - p * 3;
        int dy = p >> 1, dx = p & 1;
        float bias = b3[o];
        const size_t obase = (size_t)(b * 3 + o) * HHR * WHR;
#pragma unroll
        for (int f = 0; f < 4; ++f) {
            int n = 2 * (h0 + rowbase + f) + dy;
#pragma unroll
            for (int r = 0; r < 4; ++r) {
                int m = 2 * (w0 + lgrp * 4 + r) + dx;
                xsr[obase + (size_t)n * WHR + m] = acc[f][r] + bias;
            }
        }
    }
}

// ---------------- Boundary fixup: recompute the 1-pixel HR frame (wave/pixel) ------
__global__ void k_fix3(const ushort* __restrict__ y2, const float* __restrict__ w3,
                       const float* __restrict__ b3, float* __restrict__ xsr) {
    int wid = (blockIdx.x * blockDim.x + threadIdx.x) >> 6;
    int lane = threadIdx.x & 63;
    if (wid >= BATCH * 3 * 2044) return;
    int b = wid / (3 * 2044);
    int rem = wid - b * (3 * 2044);
    int o = rem / 2044;
    int p = rem - o * 2044;
    int n, m;
    if (p < 512) { n = 0; m = p; }
    else if (p < 1024) { n = 511; m = p - 512; }
    else if (p < 1534) { n = p - 1024 + 1; m = 0; }
    else { n = p - 1534 + 1; m = 511; }

    const int ic = lane;
    const ushort* Y = y2 + (size_t)b * HLR * WLR * 64 + ic;
    float acc = 0.f;
#pragma unroll
    for (int oh = 0; oh < 3; ++oh) {
        int r = n - 1 + oh;
        if (r < 0 || r >= HHR) continue;
        int pr = r & 1;
        int jr = (r - pr) >> 1;
        int j2 = jr + (pr ? 1 : -1);
        j2 = j2 < 0 ? 0 : (j2 > HLR - 1 ? HLR - 1 : j2);
#pragma unroll
        for (int ow = 0; ow < 3; ++ow) {
            int c = m - 1 + ow;
            if (c < 0 || c >= WHR) continue;
            int pc = c & 1;
            int kc = (c - pc) >> 1;
            int k2 = kc + (pc ? 1 : -1);
            k2 = k2 < 0 ? 0 : (k2 > WLR - 1 ? WLR - 1 : k2);
            float y00 = bf2f(Y[(size_t)(jr * WLR + kc) * 64]);
            float y01 = bf2f(Y[(size_t)(jr * WLR + k2) * 64]);
            float y10 = bf2f(Y[(size_t)(j2 * WLR + kc) * 64]);
            float y11 = bf2f(Y[(size_t)(j2 * WLR + k2) * 64]);
            float u = 0.5625f * y00 + 0.1875f * y01 + 0.1875f * y10 + 0.0625f * y11;
            acc = fmaf(w3[(size_t)(o * 64 + ic) * 9 + oh * 3 + ow], u, acc);
        }
    }
#pragma unroll
    for (int off = 32; off; off >>= 1) acc += __shfl_xor(acc, off, 64);
    if (lane == 0) xsr[((size_t)(b * 3 + o) * HHR + n) * WHR + m] = acc + b3[o];
}

extern "C" void kernel_launch(void* const* d_in, const int* in_sizes, int n_in,
                              void* d_out, int out_size, void* d_ws, size_t ws_size,
                              hipStream_t stream) {
    const float* x_hr = (const float*)d_in[0];
    const float* gains = (const float*)d_in[1];
    const float* sigp = (const float*)d_in[2];
    const float* gamp = (const float*)d_in[3];
    const float* w1 = (const float*)d_in[4];
    const float* b1 = (const float*)d_in[5];
    const float* w2 = (const float*)d_in[6];
    const float* b2 = (const float*)d_in[7];
    const float* w3 = (const float*)d_in[8];
    const float* b3 = (const float*)d_in[9];

    float* out = (float*)d_out;
    float* x_sr = out;                                  // 4*3*512*512
    float* x_lr = out + (size_t)BATCH * 3 * HHR * WHR;  // 4*3*256*256

    float* ws = (float*)d_ws;
    ushort* Bprep = (ushort*)ws;                        // 36864 bf16
    ushort* y1 = Bprep + 36864;                         // 4*256*256*64 bf16
    ushort* y2 = y1 + (size_t)BATCH * HLR * WLR * 64;   // 4*256*256*64 bf16
    ushort* Bprep3 = y2 + (size_t)BATCH * HLR * WLR * 64;  // 16384 bf16
    ushort* Bprep1 = Bprep3 + 16384;                    // 6144 bf16

    k_prepall<<<dim3(232), dim3(256), 0, stream>>>(w1, w2, w3, Bprep1, Bprep, Bprep3);
    k_downbil<<<dim3(16, 16, BATCH * 3), dim3(256), 0, stream>>>(x_hr, gains, sigp, gamp, x_lr);
    k_conv1_mfma<<<dim3(16, 64, BATCH), dim3(256), 0, stream>>>(x_lr, Bprep1, b1, y1);
    k_conv2_mfma<<<dim3(16, 16, BATCH), dim3(256), 0, stream>>>(y1, Bprep, b2, y2);
    k_upc3_mfma<<<dim3(16, 16, BATCH), dim3(256), 0, stream>>>(y2, Bprep3, b3, x_sr);
    k_fix3<<<dim3((BATCH * 3 * 2044 * 64 + 255) / 256), dim3(256), 0, stream>>>(y2, w3, b3, x_sr);
}

// Round 6
// 106.075 us; speedup vs baseline: 1.0645x; 1.0645x over previous
//
#include <hip/hip_runtime.h>
#include <math.h>

#define BATCH 4
#define HLR 256
#define WLR 256
#define HHR 512
#define WHR 512

typedef short s8v __attribute__((ext_vector_type(8)));
typedef float f4v __attribute__((ext_vector_type(4)));

__device__ __forceinline__ ushort f2bf(float f) {
    uint u = __builtin_bit_cast(uint, f);
    uint r = (u + 0x7FFFu + ((u >> 16) & 1u)) >> 16;
    return (ushort)r;
}
__device__ __forceinline__ float bf2f(ushort u) {
    return __builtin_bit_cast(float, ((uint)u) << 16);
}

// ---------------- Kernel 1: FUSED bicubic down x2 + gain + bilateral + gamma -------
__global__ void __launch_bounds__(256) k_downbil(
    const float* __restrict__ x, const float* __restrict__ gains,
    const float* __restrict__ sigp, const float* __restrict__ gamp,
    float* __restrict__ xlr) {
    __shared__ float tile[20][20];
    const int tid = threadIdx.x;
    const int tx = tid & 15, ty = tid >> 4;
    const int w0 = blockIdx.x * 16, h0 = blockIdx.y * 16;
    const int bc = blockIdx.z;
    const int c = bc % 3;
    const float* src = x + (size_t)bc * (HHR * WHR);
    const float gain = gains[c];

    const float cw0 = -0.09375f, cw1 = 0.59375f, cw2 = 0.59375f, cw3 = -0.09375f;
    for (int i = tid; i < 400; i += 256) {
        int r = i / 20, cc = i - r * 20;
        int hh = h0 + r - 2, ww = w0 + cc - 2;
        float acc = 0.f;
#pragma unroll
        for (int kh = 0; kh < 4; ++kh) {
            int sh = 2 * hh + kh - 1;
            sh = sh < 0 ? 0 : (sh > HHR - 1 ? HHR - 1 : sh);
            const float* row = src + (size_t)sh * WHR;
            float rr = 0.f;
#pragma unroll
            for (int kw = 0; kw < 4; ++kw) {
                int sw = 2 * ww + kw - 1;
                sw = sw < 0 ? 0 : (sw > WHR - 1 ? WHR - 1 : sw);
                float wk = (kw == 0) ? cw0 : (kw == 1) ? cw1 : (kw == 2) ? cw2 : cw3;
                rr = fmaf(wk, row[sw], rr);
            }
            float wk = (kh == 0) ? cw0 : (kh == 1) ? cw1 : (kh == 2) ? cw2 : cw3;
            acc = fmaf(wk, rr, acc);
        }
        tile[r][cc] = acc * gain;
    }
    __syncthreads();

    const int h = h0 + ty, w = w0 + tx;
    float sigma = sigp[0];
    float inv2s2 = 1.0f / (2.0f * sigma * sigma);
    float invg = 1.0f / gamp[0];
    const float sp0 = 0.13533528f;  // exp(-2)
    const float sp1 = 0.60653066f;  // exp(-0.5)

    float center = tile[ty + 2][tx + 2];
    float wsum = 0.f, psum = 0.f;
#pragma unroll
    for (int i = 0; i < 5; ++i) {
        int sh = h + i - 2;
        sh = sh < 0 ? -sh : (sh > HLR - 1 ? 2 * (HLR - 1) - sh : sh);  // reflect
        int lr = sh - h0 + 2;
        float spi = (i == 0 || i == 4) ? sp0 : (i == 2 ? 1.0f : sp1);
#pragma unroll
        for (int j = 0; j < 5; ++j) {
            int sw = w + j - 2;
            sw = sw < 0 ? -sw : (sw > WLR - 1 ? 2 * (WLR - 1) - sw : sw);
            int lc = sw - w0 + 2;
            float spj = (j == 0 || j == 4) ? sp0 : (j == 2 ? 1.0f : sp1);
            float p = tile[lr][lc];
            float d = p - center;
            float cwt = __expf(-d * d * inv2s2) * spi * spj;
            wsum += cwt;
            psum = fmaf(cwt, p, psum);
        }
    }
    float v = psum / (wsum + 1e-8f);
    v = fminf(fmaxf(v, 1e-8f), 1.0f);
    xlr[(size_t)bc * (HLR * WLR) + h * WLR + w] = __powf(v, invg);
}

// --------- Effective upsample weight: Av(d, e_idx, t_idx), taps t-1 in {-1..2} -----
__device__ __forceinline__ float Avf(int d, int e, int t) {
    int mm = d + e - 1;
    int par = mm & 1;
    int jr = (mm - par) >> 1;
    int j2 = jr + (par ? 1 : -1);
    float a = 0.f;
    if (t == jr + 1) a += 0.75f;
    if (t == j2 + 1) a += 0.25f;
    return a;
}

// ---------------- Merged weight prep: all three B-fragment tensors -----------------
__global__ void k_prepall(const float* __restrict__ w1, const float* __restrict__ w2,
                          const float* __restrict__ w3, ushort* __restrict__ Bp1,
                          ushort* __restrict__ Bp2, ushort* __restrict__ Bp3) {
    int bx = blockIdx.x;
    if (bx < 144) {
        int tid = bx * 256 + threadIdx.x;
        int j = tid & 7;
        int l = (tid >> 3) & 63;
        int g = (tid >> 9) & 3;
        int s = tid >> 11;
        int k = 32 * s + (l >> 4) * 8 + j;
        int t = k >> 6;
        int ic = k & 63;
        int oc = g * 16 + (l & 15);
        Bp2[tid] = f2bf(w2[(size_t)(oc * 64 + ic) * 9 + t]);
    } else if (bx < 208) {
        int tid = (bx - 144) * 256 + threadIdx.x;
        int j = tid & 7;
        int l = (tid >> 3) & 63;
        int s = tid >> 9;
        int col = l & 15;
        float v = 0.f;
        if (col < 12) {
            int p = col / 3, o = col % 3;
            int dy = p >> 1, dx = p & 1;
            int k = s * 32 + (l >> 4) * 8 + j;
            int tap = k >> 6, ic = k & 63;
            int ty = tap >> 2, tx = tap & 3;
#pragma unroll
            for (int oh = 0; oh < 3; ++oh)
#pragma unroll
                for (int ow = 0; ow < 3; ++ow)
                    v += w3[(size_t)(o * 64 + ic) * 9 + oh * 3 + ow] *
                         Avf(dy, oh, ty) * Avf(dx, ow, tx);
        }
        Bp3[tid] = f2bf(v);
    } else {
        int tid = (bx - 208) * 256 + threadIdx.x;
        int j = tid & 7;
        int l = (tid >> 3) & 63;
        int g = (tid >> 9) & 3;
        int s = tid >> 11;
        int k = s * 32 + (l >> 4) * 8 + j;
        int oc = g * 16 + (l & 15);
        float v = 0.f;
        if (k < 75) {
            int tap = k / 3, ic = k % 3;
            v = w1[(size_t)oc * 75 + ic * 25 + tap];
        }
        Bp1[tid] = f2bf(v);
    }
}

// ---------------- Kernel 3: conv1 3->64, 5x5, pad 2, relu — MFMA implicit GEMM ----
__global__ void __launch_bounds__(256) k_conv1_mfma(
    const float* __restrict__ xlr, const ushort* __restrict__ Bp,
    const float* __restrict__ b1, ushort* __restrict__ y1) {
    __shared__ float rawt[3][8][20];
    __shared__ __align__(16) ushort Alds[64 * 104];
    const int tid = threadIdx.x;
    const int w0 = blockIdx.x * 16;
    const int h0 = blockIdx.y * 4;
    const int b = blockIdx.z;

    for (int i = tid; i < 480; i += 256) {
        int ch = i / 160;
        int rem = i - ch * 160;
        int r = rem / 20, c = rem - r * 20;
        int gh = h0 + r - 2, gw = w0 + c - 2;
        float v = 0.f;
        if (gh >= 0 && gh < HLR && gw >= 0 && gw < WLR)
            v = xlr[(size_t)(b * 3 + ch) * (HLR * WLR) + gh * WLR + gw];
        rawt[ch][r][c] = v;
    }
    __syncthreads();

    {
        const int pos = tid >> 2;
        const int kq = tid & 3;
        const int f = pos >> 4;
        const int wl = pos & 15;
#pragma unroll
        for (int m = 0; m < 3; ++m) {
            uint pk[4];
#pragma unroll
            for (int e2 = 0; e2 < 4; ++e2) {
                ushort lo, hi;
#pragma unroll
                for (int h2 = 0; h2 < 2; ++h2) {
                    int i = m * 8 + e2 * 2 + h2;
                    int t0 = i / 3;
                    int ic = i - t0 * 3;
                    int tap = kq * 8 + t0;
                    float val = 0.f;
                    if (tap < 25) {
                        int kh = tap / 5, kw = tap - (tap / 5) * 5;
                        val = rawt[ic][f + kh][wl + kw];
                    }
                    if (h2 == 0) lo = f2bf(val); else hi = f2bf(val);
                }
                pk[e2] = (uint)lo | ((uint)hi << 16);
            }
            *(int4*)(Alds + pos * 104 + kq * 24 + m * 8) =
                make_int4(pk[0], pk[1], pk[2], pk[3]);
        }
    }
    __syncthreads();

    const int lane = tid & 63;
    const int wv = tid >> 6;
    const int l15 = lane & 15;
    const int lgrp = lane >> 4;

    f4v acc[4];
#pragma unroll
    for (int f = 0; f < 4; ++f) acc[f] = (f4v){0.f, 0.f, 0.f, 0.f};

#pragma unroll
    for (int s = 0; s < 3; ++s) {
        s8v bfrag = *(const s8v*)(Bp + ((size_t)(s * 4 + wv) * 64 + lane) * 8);
#pragma unroll
        for (int f = 0; f < 4; ++f) {
            const ushort* ap = Alds + (f * 16 + l15) * 104 + s * 32 + lgrp * 8;
            s8v afrag = *(const s8v*)ap;
            acc[f] = __builtin_amdgcn_mfma_f32_16x16x32_bf16(afrag, bfrag, acc[f], 0, 0, 0);
        }
    }

    int oc = wv * 16 + l15;
    float bias = b1[oc];
    const size_t base = (size_t)b * HLR * WLR * 64;
#pragma unroll
    for (int f = 0; f < 4; ++f) {
        int h = h0 + f;
#pragma unroll
        for (int r = 0; r < 4; ++r) {
            int w = w0 + lgrp * 4 + r;
            float v = fmaxf(acc[f][r] + bias, 0.f);
            y1[base + (size_t)(h * WLR + w) * 64 + oc] = f2bf(v);
        }
    }
}

// ---------------- Kernel 4: conv2 64->64, 3x3, pad1, relu — MFMA (4-row tile) ------
// REVERTED to round-4 structure: 13.8 KB LDS, 4096 blocks -> high occupancy carries it.
__global__ void __launch_bounds__(256) k_conv2_mfma(
    const ushort* __restrict__ y1, const ushort* __restrict__ Bprep,
    const float* __restrict__ b2, ushort* __restrict__ y2) {
    __shared__ ushort lds[6 * 18 * 64];  // 13824 B
    const int tid = threadIdx.x;
    const int w0 = blockIdx.x * 16;
    const int h0 = blockIdx.y * 4;
    const int b = blockIdx.z;
    const size_t base = (size_t)b * HLR * WLR * 64;

    for (int i = tid; i < 864; i += 256) {
        int c = i & 7;
        int pos = i >> 3;
        int r = pos / 18;
        int cc = pos - r * 18;
        int gh = h0 + r - 1, gw = w0 + cc - 1;
        int4 v = make_int4(0, 0, 0, 0);
        if (gh >= 0 && gh < HLR && gw >= 0 && gw < WLR)
            v = *(const int4*)(y1 + base + (size_t)(gh * WLR + gw) * 64 + c * 8);
        int byte = pos * 128 + ((c * 16) ^ ((pos & 7) << 4));
        *(int4*)((char*)lds + byte) = v;
    }
    __syncthreads();

    const int lane = tid & 63;
    const int wv = tid >> 6;
    const int l15 = lane & 15;
    const int lgrp = lane >> 4;

    f4v acc[4];
#pragma unroll
    for (int f = 0; f < 4; ++f) acc[f] = (f4v){0.f, 0.f, 0.f, 0.f};

    const ushort* bp = Bprep + ((size_t)wv * 64 + lane) * 8;
#pragma unroll
    for (int s = 0; s < 18; ++s) {
        const int t = s >> 1;
        const int dh = t / 3 - 1;
        const int dw = t % 3 - 1;
        const int icb = (s & 1) * 64 + lgrp * 16;
        s8v bfrag = *(const s8v*)(bp + (size_t)s * (4 * 64 * 8));
#pragma unroll
        for (int f = 0; f < 4; ++f) {
            int sp = (f + dh + 1) * 18 + (l15 + dw + 1);
            int byte = sp * 128 + (icb ^ ((sp & 7) << 4));
            s8v afrag = *(const s8v*)((const char*)lds + byte);
            acc[f] = __builtin_amdgcn_mfma_f32_16x16x32_bf16(afrag, bfrag, acc[f], 0, 0, 0);
        }
    }

    int oc = wv * 16 + l15;
    float bias = b2[oc];
#pragma unroll
    for (int f = 0; f < 4; ++f) {
        int h = h0 + f;
#pragma unroll
        for (int r = 0; r < 4; ++r) {
            int w = w0 + lgrp * 4 + r;
            float v = fmaxf(acc[f][r] + bias, 0.f);
            y2[base + (size_t)(h * WLR + w) * 64 + oc] = f2bf(v);
        }
    }
}

// ---------------- Kernel 5: fused upsample+conv3 as MFMA 4x4-tap 64->12 conv -------
__global__ void __launch_bounds__(256) k_upc3_mfma(
    const ushort* __restrict__ y2, const ushort* __restrict__ Bp,
    const float* __restrict__ b3, float* __restrict__ xsr) {
    __shared__ ushort lds[19 * 19 * 64];  // 46208 B
    const int tid = threadIdx.x;
    const int w0 = blockIdx.x * 16;
    const int h0 = blockIdx.y * 16;
    const int b = blockIdx.z;
    const size_t base = (size_t)b * HLR * WLR * 64;

    for (int i = tid; i < 2888; i += 256) {
        int c = i & 7;
        int pos = i >> 3;
        int r = pos / 19, cc = pos - r * 19;
        int gh = h0 + r - 1, gw = w0 + cc - 1;
        gh = gh < 0 ? 0 : (gh > HLR - 1 ? HLR - 1 : gh);
        gw = gw < 0 ? 0 : (gw > WLR - 1 ? WLR - 1 : gw);
        int4 v = *(const int4*)(y2 + base + (size_t)(gh * WLR + gw) * 64 + c * 8);
        int byte = pos * 128 + ((c * 16) ^ ((pos & 7) << 4));
        *(int4*)((char*)lds + byte) = v;
    }
    __syncthreads();

    const int lane = tid & 63;
    const int wv = tid >> 6;
    const int l15 = lane & 15;
    const int lgrp = lane >> 4;
    const int rowbase = wv * 4;

    f4v acc[4];
#pragma unroll
    for (int f = 0; f < 4; ++f) acc[f] = (f4v){0.f, 0.f, 0.f, 0.f};

    const ushort* bp = Bp + (size_t)lane * 8;
#pragma unroll
    for (int s = 0; s < 32; ++s) {
        s8v bfrag = *(const s8v*)(bp + (size_t)s * 512);
        const int tap = s >> 1;
        const int ty = tap >> 2, tx = tap & 3;
        const int icb = (s & 1) * 64 + lgrp * 16;
#pragma unroll
        for (int f = 0; f < 4; ++f) {
            int pos = (rowbase + f + ty) * 19 + (l15 + tx);
            int byte = pos * 128 + (icb ^ ((pos & 7) << 4));
            s8v afrag = *(const s8v*)((const char*)lds + byte);
            acc[f] = __builtin_amdgcn_mfma_f32_16x16x32_bf16(afrag, bfrag, acc[f], 0, 0, 0);
        }
    }

    if (l15 < 12) {
        int p = l15 / 3, o = l15 - p * 3;
        int dy = p >> 1, dx = p & 1;
        float bias = b3[o];
        const size_t obase = (size_t)(b * 3 + o) * HHR * WHR;
#pragma unroll
        for (int f = 0; f < 4; ++f) {
            int n = 2 * (h0 + rowbase + f) + dy;
#pragma unroll
            for (int r = 0; r < 4; ++r) {
                int m = 2 * (w0 + lgrp * 4 + r) + dx;
                xsr[obase + (size_t)n * WHR + m] = acc[f][r] + bias;
            }
        }
    }
}

// ---------------- Boundary fixup: recompute the 1-pixel HR frame (wave/pixel) ------
__global__ void k_fix3(const ushort* __restrict__ y2, const float* __restrict__ w3,
                       const float* __restrict__ b3, float* __restrict__ xsr) {
    int wid = (blockIdx.x * blockDim.x + threadIdx.x) >> 6;
    int lane = threadIdx.x & 63;
    if (wid >= BATCH * 3 * 2044) return;
    int b = wid / (3 * 2044);
    int rem = wid - b * (3 * 2044);
    int o = rem / 2044;
    int p = rem - o * 2044;
    int n, m;
    if (p < 512) { n = 0; m = p; }
    else if (p < 1024) { n = 511; m = p - 512; }
    else if (p < 1534) { n = p - 1024 + 1; m = 0; }
    else { n = p - 1534 + 1; m = 511; }

    const int ic = lane;
    const ushort* Y = y2 + (size_t)b * HLR * WLR * 64 + ic;
    float acc = 0.f;
#pragma unroll
    for (int oh = 0; oh < 3; ++oh) {
        int r = n - 1 + oh;
        if (r < 0 || r >= HHR) continue;
        int pr = r & 1;
        int jr = (r - pr) >> 1;
        int j2 = jr + (pr ? 1 : -1);
        j2 = j2 < 0 ? 0 : (j2 > HLR - 1 ? HLR - 1 : j2);
#pragma unroll
        for (int ow = 0; ow < 3; ++ow) {
            int c = m - 1 + ow;
            if (c < 0 || c >= WHR) continue;
            int pc = c & 1;
            int kc = (c - pc) >> 1;
            int k2 = kc + (pc ? 1 : -1);
            k2 = k2 < 0 ? 0 : (k2 > WLR - 1 ? WLR - 1 : k2);
            float y00 = bf2f(Y[(size_t)(jr * WLR + kc) * 64]);
            float y01 = bf2f(Y[(size_t)(jr * WLR + k2) * 64]);
            float y10 = bf2f(Y[(size_t)(j2 * WLR + kc) * 64]);
            float y11 = bf2f(Y[(size_t)(j2 * WLR + k2) * 64]);
            float u = 0.5625f * y00 + 0.1875f * y01 + 0.1875f * y10 + 0.0625f * y11;
            acc = fmaf(w3[(size_t)(o * 64 + ic) * 9 + oh * 3 + ow], u, acc);
        }
    }
#pragma unroll
    for (int off = 32; off; off >>= 1) acc += __shfl_xor(acc, off, 64);
    if (lane == 0) xsr[((size_t)(b * 3 + o) * HHR + n) * WHR + m] = acc + b3[o];
}

extern "C" void kernel_launch(void* const* d_in, const int* in_sizes, int n_in,
                              void* d_out, int out_size, void* d_ws, size_t ws_size,
                              hipStream_t stream) {
    const float* x_hr = (const float*)d_in[0];
    const float* gains = (const float*)d_in[1];
    const float* sigp = (const float*)d_in[2];
    const float* gamp = (const float*)d_in[3];
    const float* w1 = (const float*)d_in[4];
    const float* b1 = (const float*)d_in[5];
    const float* w2 = (const float*)d_in[6];
    const float* b2 = (const float*)d_in[7];
    const float* w3 = (const float*)d_in[8];
    const float* b3 = (const float*)d_in[9];

    float* out = (float*)d_out;
    float* x_sr = out;                                  // 4*3*512*512
    float* x_lr = out + (size_t)BATCH * 3 * HHR * WHR;  // 4*3*256*256

    float* ws = (float*)d_ws;
    ushort* Bprep = (ushort*)ws;                        // 36864 bf16
    ushort* y1 = Bprep + 36864;                         // 4*256*256*64 bf16
    ushort* y2 = y1 + (size_t)BATCH * HLR * WLR * 64;   // 4*256*256*64 bf16
    ushort* Bprep3 = y2 + (size_t)BATCH * HLR * WLR * 64;  // 16384 bf16
    ushort* Bprep1 = Bprep3 + 16384;                    // 6144 bf16

    k_prepall<<<dim3(232), dim3(256), 0, stream>>>(w1, w2, w3, Bprep1, Bprep, Bprep3);
    k_downbil<<<dim3(16, 16, BATCH * 3), dim3(256), 0, stream>>>(x_hr, gains, sigp, gamp, x_lr);
    k_conv1_mfma<<<dim3(16, 64, BATCH), dim3(256), 0, stream>>>(x_lr, Bprep1, b1, y1);
    k_conv2_mfma<<<dim3(16, 64, BATCH), dim3(256), 0, stream>>>(y1, Bprep, b2, y2);
    k_upc3_mfma<<<dim3(16, 16, BATCH), dim3(256), 0, stream>>>(y2, Bprep3, b3, x_sr);
    k_fix3<<<dim3((BATCH * 3 * 2044 * 64 + 255) / 256), dim3(256), 0, stream>>>(y2, w3, b3, x_sr);
}